// Round 2
// baseline (29204.074 us; speedup 1.0000x reference)
//
#include <hip/hip_runtime.h>

#define TSTEPS 512
#define BATCH  256
#define HID    256
#define OUTC   256

typedef _Float16 half8 __attribute__((ext_vector_type(8)));
typedef float    f32x4 __attribute__((ext_vector_type(4)));

__device__ __forceinline__ float sigf(float x){ return 1.0f/(1.0f+__expf(-x)); }
__device__ __forceinline__ float tanh_(float x){
  float a = fminf(fmaxf(x,-8.0f),8.0f);
  float e = __expf(2.0f*a);
  return (e-1.0f)/(e+1.0f);
}

// ---------------- prep: f32 -> f16 weight conversion + bias fold ----------------
__global__ void prep_convert(const float* __restrict__ Wih, const float* __restrict__ Whh,
                             const float* __restrict__ fcw, const float* __restrict__ bih,
                             const float* __restrict__ bhh,
                             _Float16* __restrict__ wh0, _Float16* __restrict__ wi1,
                             _Float16* __restrict__ wh1, _Float16* __restrict__ fcwh,
                             float* __restrict__ bias1)
{
  int i = blockIdx.x*256 + threadIdx.x;          // grid covers exactly 262144
  wh0[i] = (_Float16)Whh[i];                     // W_hh[0]
  wi1[i] = (_Float16)Wih[262144 + i];            // W_ih[1]
  wh1[i] = (_Float16)Whh[262144 + i];            // W_hh[1]
  if (i < 65536) fcwh[i] = (_Float16)fcw[i];
  if (i < 1024)  bias1[i] = bih[1024+i] + bhh[1024+i];
}

// ---------------- prep: gx0[b][n] = x[b]·W_ih0[n] + b_ih0[n] + b_hh0[n] (f32) ----
__global__ void prep_gx0(const float* __restrict__ x, const float* __restrict__ Wih,
                         const float* __restrict__ bih, const float* __restrict__ bhh,
                         float* __restrict__ gx0)
{
  int gid = blockIdx.x*256 + threadIdx.x;        // 262144 outputs
  int b = gid >> 10, n = gid & 1023;
  const float4* xv = (const float4*)(x + (size_t)b*256);
  const float4* wv = (const float4*)(Wih + (size_t)n*256);
  float s = bih[n] + bhh[n];
  #pragma unroll 8
  for (int k=0;k<64;k++){
    float4 a = xv[k], c = wv[k];
    s += a.x*c.x + a.y*c.y + a.z*c.z + a.w*c.w;
  }
  gx0[gid] = s;
}

__global__ void zero_cnt(unsigned* __restrict__ c){
  c[blockIdx.x*256 + threadIdx.x] = 0u;          // 8192 words, 32 blocks
}

// ---------------- distributed LSTM: 128 WGs = 8 batch-tiles x 16 j-slices --------
// WG(bt,js): 32 batch rows x 16 hidden cols, all 4 gates, both layers.
// Weights for the slice live in LDS (loaded once). h exchanged via L2 each step.
// wave wv: gate w=wv&3, m-tile m=wv>>2; lane: jj=l&15 (M/N index), kg=l>>4.
// MFMA C layout (validated round 0): C[row=kg*4+r][col=l&15].
__global__ __launch_bounds__(512, 2) void lstm2(
    const float* __restrict__ gx0, const _Float16* __restrict__ Wh0g,
    const _Float16* __restrict__ Wi1g, const _Float16* __restrict__ Wh1g,
    const float* __restrict__ bias1, const float* __restrict__ h0_in,
    const float* __restrict__ c0_in, _Float16* __restrict__ seq, int pitch,
    _Float16* __restrict__ h0x, _Float16* __restrict__ h1x,
    unsigned* __restrict__ cnt)
{
  __shared__ _Float16 sh0[32][256];      // 16 KB  h0 tile (swizzled)
  __shared__ _Float16 sh1[32][256];      // 16 KB  h1 tile (swizzled)
  __shared__ _Float16 W0s[4][16][256];   // 32 KB  Wh0 slice
  __shared__ _Float16 W1s[4][16][512];   // 64 KB  [Wi1|Wh1] slice
  __shared__ float    gbuf[4][32][16];   //  8 KB  gate staging

  const int blk = blockIdx.x;
  const int bt  = blk & 7;               // batch tile (XCD-local group)
  const int js  = blk >> 3;              // j-slice 0..15
  const int b0  = bt * 32;
  const int jb  = js * 16;
  const int tid = threadIdx.x;
  const int wv  = tid >> 6;
  const int w   = wv & 3;                // gate index
  const int m   = wv >> 2;               // m-tile (0/1)
  const int l   = tid & 63;
  const int jj  = l & 15;
  const int kg  = l >> 4;

  // ---- weights -> LDS, swizzled: granule g16 stored at (g16 ^ (row&7)) ----
  for (int idx = tid; idx < 2048; idx += 512){
    int row = idx >> 5, gr = idx & 31;
    int g = row >> 4, j = row & 15;
    half8 v = *(const half8*)(Wh0g + ((size_t)(g*256 + jb + j))*256 + gr*8);
    *(half8*)&W0s[g][j][(gr ^ (j&7))*8] = v;
  }
  for (int idx = tid; idx < 4096; idx += 512){
    int row = idx >> 6, gr = idx & 63;
    int g = row >> 4, j = row & 15;
    const _Float16* src = (gr < 32)
        ? (Wi1g + ((size_t)(g*256 + jb + j))*256 + gr*8)
        : (Wh1g + ((size_t)(g*256 + jb + j))*256 + (size_t)(gr-32)*8);
    *(half8*)&W1s[g][j][(gr ^ (j&7))*8] = *(const half8*)src;
  }
  // ---- init h tiles ----
  for (int gidx = tid; gidx < 1024; gidx += 512){
    int row = gidx >> 5, gr = gidx & 31;
    const float* s0 = h0_in + ((size_t)(b0+row))*256 + gr*8;
    const float* s1 = s0 + 65536;
    half8 v0, v1;
    #pragma unroll
    for (int q=0;q<8;q++){ v0[q]=(_Float16)s0[q]; v1[q]=(_Float16)s1[q]; }
    *(half8*)&sh0[row][(gr ^ (row&7))*8] = v0;
    *(half8*)&sh1[row][(gr ^ (row&7))*8] = v1;
  }
  // ---- per-thread persistent state ----
  const int eb = tid >> 4;               // elementwise batch row 0..31
  const int ej = tid & 15;               // elementwise j within slice
  float c0v = c0_in[((size_t)(b0+eb))*256 + jb + ej];
  float c1v = c0_in[65536 + ((size_t)(b0+eb))*256 + jb + ej];
  float gxr[4];
  #pragma unroll
  for (int r=0;r<4;r++)
    gxr[r] = gx0[((size_t)(b0 + m*16 + kg*4 + r))*1024 + w*256 + jb + jj];
  const float bv = bias1[w*256 + jb + jj];

  unsigned* cA = cnt + bt*512;
  unsigned* cB = cnt + 4096 + bt*512;
  const int ar = m*16 + jj;              // A-fragment row (batch, within tile)
  __syncthreads();

  for (int t = 0; t < TSTEPS; ++t){
    const int p = t & 1;
    // ===== layer 0: gates = gx0 + h0 @ Wh0^T =====
    f32x4 acc  = { gxr[0], gxr[1], gxr[2], gxr[3] };
    f32x4 accb = { 0.f, 0.f, 0.f, 0.f };
    #pragma unroll
    for (int kt = 0; kt < 8; kt += 2){
      half8 a0 = *(const half8*)&sh0[ar][(((kt  )*4+kg) ^ (jj&7))*8];
      half8 a1 = *(const half8*)&sh0[ar][(((kt+1)*4+kg) ^ (jj&7))*8];
      half8 b0 = *(const half8*)&W0s[w][jj][(((kt  )*4+kg) ^ (jj&7))*8];
      half8 b1 = *(const half8*)&W0s[w][jj][(((kt+1)*4+kg) ^ (jj&7))*8];
      acc  = __builtin_amdgcn_mfma_f32_16x16x32_f16(a0, b0, acc , 0,0,0);
      accb = __builtin_amdgcn_mfma_f32_16x16x32_f16(a1, b1, accb, 0,0,0);
    }
    acc += accb;
    #pragma unroll
    for (int r=0;r<4;r++) gbuf[w][m*16+kg*4+r][jj] = acc[r];
    __syncthreads();
    {  // elementwise layer 0
      float iv = sigf (gbuf[0][eb][ej]);
      float fv = sigf (gbuf[1][eb][ej]);
      float gv = tanh_(gbuf[2][eb][ej]);
      float ov = sigf (gbuf[3][eb][ej]);
      c0v = fv*c0v + iv*gv;
      float hn = ov*tanh_(c0v);
      h0x[(size_t)p*65536 + ((size_t)(b0+eb))*256 + jb + ej] = (_Float16)hn;
    }
    __threadfence();
    __syncthreads();
    if (tid == 0)
      __hip_atomic_fetch_add(&cA[t], 1u, __ATOMIC_RELEASE, __HIP_MEMORY_SCOPE_AGENT);

    // ---- refresh sh1 from step t-1's h1 exchange (lagging barrier) ----
    if (t > 0){
      if (tid == 0){
        while (__hip_atomic_load(&cB[t-1], __ATOMIC_RELAXED, __HIP_MEMORY_SCOPE_AGENT) < 16u)
          __builtin_amdgcn_s_sleep(1);
      }
      __syncthreads();
      __builtin_amdgcn_fence(__ATOMIC_ACQUIRE, "agent");
      const _Float16* src = h1x + (size_t)((t-1)&1)*65536 + (size_t)b0*256;
      #pragma unroll
      for (int it = 0; it < 2; ++it){
        int gidx = tid + it*512;
        int row = gidx >> 5, gr = gidx & 31;
        half8 v = *(const half8*)(src + (size_t)row*256 + gr*8);
        *(half8*)&sh1[row][(gr ^ (row&7))*8] = v;
      }
      __syncthreads();
    }
    // ===== layer 1 part A: Wh1 · h1_prev  (overlaps the h0 exchange) =====
    f32x4 acc1  = { bv, bv, bv, bv };
    f32x4 acc1b = { 0.f, 0.f, 0.f, 0.f };
    #pragma unroll
    for (int kt = 0; kt < 8; kt += 2){
      half8 a0 = *(const half8*)&sh1[ar][(((kt  )*4+kg) ^ (jj&7))*8];
      half8 a1 = *(const half8*)&sh1[ar][(((kt+1)*4+kg) ^ (jj&7))*8];
      half8 b0 = *(const half8*)&W1s[w][jj][((32+(kt  )*4+kg) ^ (jj&7))*8];
      half8 b1 = *(const half8*)&W1s[w][jj][((32+(kt+1)*4+kg) ^ (jj&7))*8];
      acc1  = __builtin_amdgcn_mfma_f32_16x16x32_f16(a0, b0, acc1 , 0,0,0);
      acc1b = __builtin_amdgcn_mfma_f32_16x16x32_f16(a1, b1, acc1b, 0,0,0);
    }
    // ---- wait for this step's h0_new from all 16 slice-WGs ----
    if (tid == 0){
      while (__hip_atomic_load(&cA[t], __ATOMIC_RELAXED, __HIP_MEMORY_SCOPE_AGENT) < 16u)
        __builtin_amdgcn_s_sleep(1);
    }
    __syncthreads();
    __builtin_amdgcn_fence(__ATOMIC_ACQUIRE, "agent");
    {
      const _Float16* src = h0x + (size_t)p*65536 + (size_t)b0*256;
      #pragma unroll
      for (int it = 0; it < 2; ++it){
        int gidx = tid + it*512;
        int row = gidx >> 5, gr = gidx & 31;
        half8 v = *(const half8*)(src + (size_t)row*256 + gr*8);
        *(half8*)&sh0[row][(gr ^ (row&7))*8] = v;
      }
    }
    __syncthreads();
    // ===== layer 1 part B: += Wi1 · h0_new =====
    #pragma unroll
    for (int kt = 0; kt < 8; kt += 2){
      half8 a0 = *(const half8*)&sh0[ar][(((kt  )*4+kg) ^ (jj&7))*8];
      half8 a1 = *(const half8*)&sh0[ar][(((kt+1)*4+kg) ^ (jj&7))*8];
      half8 b0 = *(const half8*)&W1s[w][jj][(((kt  )*4+kg) ^ (jj&7))*8];
      half8 b1 = *(const half8*)&W1s[w][jj][(((kt+1)*4+kg) ^ (jj&7))*8];
      acc1  = __builtin_amdgcn_mfma_f32_16x16x32_f16(a0, b0, acc1 , 0,0,0);
      acc1b = __builtin_amdgcn_mfma_f32_16x16x32_f16(a1, b1, acc1b, 0,0,0);
    }
    acc1 += acc1b;
    #pragma unroll
    for (int r=0;r<4;r++) gbuf[w][m*16+kg*4+r][jj] = acc1[r];
    __syncthreads();
    {  // elementwise layer 1 + publish
      float iv = sigf (gbuf[0][eb][ej]);
      float fv = sigf (gbuf[1][eb][ej]);
      float gv = tanh_(gbuf[2][eb][ej]);
      float ov = sigf (gbuf[3][eb][ej]);
      c1v = fv*c1v + iv*gv;
      float hn = ov*tanh_(c1v);
      _Float16 hh = (_Float16)hn;
      h1x[(size_t)p*65536 + ((size_t)(b0+eb))*256 + jb + ej] = hh;
      seq[((size_t)(b0+eb)*TSTEPS + t)*(size_t)pitch + jb + ej] = hh;
    }
    __threadfence();
    __syncthreads();
    if (tid == 0)
      __hip_atomic_fetch_add(&cB[t], 1u, __ATOMIC_RELEASE, __HIP_MEMORY_SCOPE_AGENT);
  }
}

// ---------------- FC + log_softmax / softmax ----------------
__global__ __launch_bounds__(256) void fc_kernel(
    const _Float16* __restrict__ seq, int pitch,
    const _Float16* __restrict__ fcwh, const float* __restrict__ fcb,
    float* __restrict__ out0, float* __restrict__ out1)
{
  const int tid = threadIdx.x;
  const int w = tid >> 6, l = tid & 63;
  const int col = l & 15, kg = l >> 4;
  const size_t m0 = (size_t)blockIdx.x*64 + (size_t)w*16;   // flat (b*T+t) row base
  half8 a[8];
  #pragma unroll
  for (int kt=0;kt<8;kt++)
    a[kt] = *(const half8*)&seq[(m0+col)*(size_t)pitch + kt*32 + kg*8];
  f32x4 acc[16];
  #pragma unroll
  for (int nt=0;nt<16;nt++){
    int n = nt*16 + col;
    float bvl = fcb[n];
    f32x4 c = {bvl,bvl,bvl,bvl};
    const _Float16* wr = fcwh + (size_t)n*256;
    #pragma unroll
    for (int kt=0;kt<8;kt++){
      half8 bf = *(const half8*)&wr[kt*32 + kg*8];
      c = __builtin_amdgcn_mfma_f32_16x16x32_f16(a[kt], bf, c, 0,0,0);
    }
    acc[nt] = c;
  }
  #pragma unroll
  for (int r=0;r<4;r++){
    float mx = -3.0e38f;
    #pragma unroll
    for (int nt=0;nt<16;nt++) mx = fmaxf(mx, acc[nt][r]);
    #pragma unroll
    for (int off=1; off<16; off<<=1) mx = fmaxf(mx, __shfl_xor(mx, off, 64));
    float s = 0.0f;
    #pragma unroll
    for (int nt=0;nt<16;nt++) s += __expf(acc[nt][r]-mx);
    #pragma unroll
    for (int off=1; off<16; off<<=1) s += __shfl_xor(s, off, 64);
    float inv = 1.0f/s;
    float ls  = __logf(s);
    size_t row = m0 + (size_t)kg*4 + r;
    #pragma unroll
    for (int nt=0;nt<16;nt++){
      int n = nt*16 + col;
      float v = acc[nt][r]-mx;
      out0[row*256 + n] = v - ls;        // log_softmax
      out1[row*256 + n] = __expf(v)*inv; // softmax
    }
  }
}

extern "C" void kernel_launch(void* const* d_in, const int* in_sizes, int n_in,
                              void* d_out, int out_size, void* d_ws, size_t ws_size,
                              hipStream_t stream)
{
  const float* x   = (const float*)d_in[0];
  const float* h0  = (const float*)d_in[1];
  const float* c0  = (const float*)d_in[2];
  const float* Wih = (const float*)d_in[3];
  const float* Whh = (const float*)d_in[4];
  const float* bih = (const float*)d_in[5];
  const float* bhh = (const float*)d_in[6];
  const float* fcw = (const float*)d_in[7];
  const float* fcb = (const float*)d_in[8];
  (void)in_sizes; (void)n_in; (void)out_size;

  char* ws = (char*)d_ws;
  _Float16* wh0   = (_Float16*)(ws + 0);            // 512 KB
  _Float16* wi1   = (_Float16*)(ws + (512<<10));    // 512 KB
  _Float16* wh1   = (_Float16*)(ws + (1024<<10));   // 512 KB
  _Float16* fcwh  = (_Float16*)(ws + (1536<<10));   // 128 KB
  float*    bias1 = (float*)   (ws + (1664<<10));   // 4 KB
  float*    gx0   = (float*)   (ws + (1668<<10));   // 1 MB  (ends 2692 KB)

  // scratch for the exchange protocol lives in out0 (fully overwritten by fc)
  float* out0 = (float*)d_out;
  float* out1 = out0 + (size_t)BATCH*TSTEPS*OUTC;
  unsigned*  cnt = (unsigned*)d_out;                            // 32 KB
  _Float16*  h0x = (_Float16*)((char*)d_out + (1<<20));         // 256 KB
  _Float16*  h1x = (_Float16*)((char*)d_out + (1<<20) + 262144);// 256 KB

  const size_t SEQ_OFF   = 3ull<<20;
  const size_t seq_bytes = (size_t)BATCH*TSTEPS*HID*sizeof(_Float16); // 64 MB
  _Float16* seq; int pitch;
  if (ws_size >= SEQ_OFF + seq_bytes){
    seq = (_Float16*)(ws + SEQ_OFF); pitch = HID;   // packed in workspace
  } else {
    // overlay seq (f16, 512B/row) inside out1's 1KB/row slots; fc_kernel
    // reads each row into registers before overwriting the slot (same wave).
    seq = (_Float16*)out1; pitch = 512;
  }

  hipLaunchKernelGGL(zero_cnt, dim3(32), dim3(256), 0, stream, cnt);
  hipLaunchKernelGGL(prep_convert, dim3(1024), dim3(256), 0, stream,
                     Wih, Whh, fcw, bih, bhh, wh0, wi1, wh1, fcwh, bias1);
  hipLaunchKernelGGL(prep_gx0, dim3(1024), dim3(256), 0, stream,
                     x, Wih, bih, bhh, gx0);
  hipLaunchKernelGGL(lstm2, dim3(128), dim3(512), 0, stream,
                     gx0, wh0, wi1, wh1, bias1, h0, c0, seq, pitch,
                     h0x, h1x, cnt);
  hipLaunchKernelGGL(fc_kernel, dim3(2048), dim3(256), 0, stream,
                     seq, pitch, fcwh, fcb, out0, out1);
}

// Round 3
// 3253.107 us; speedup vs baseline: 8.9773x; 8.9773x over previous
//
#include <hip/hip_runtime.h>

#define TSTEPS 512
#define BATCH  256
#define HID    256
#define OUTC   256

typedef _Float16 half8 __attribute__((ext_vector_type(8)));
typedef float    f32x4 __attribute__((ext_vector_type(4)));

union G16 { unsigned long long u2[2]; unsigned u[4]; half8 h; };

__device__ __forceinline__ float sigf(float x){ return 1.0f/(1.0f+__expf(-x)); }
__device__ __forceinline__ float tanh_(float x){
  float a = fminf(fmaxf(x,-8.0f),8.0f);
  float e = __expf(2.0f*a);
  return (e-1.0f)/(e+1.0f);
}

// relaxed agent-scope ops: sc1 data path through L3, no cache-wide fences
__device__ __forceinline__ void st_x(unsigned* p, unsigned v){
  __hip_atomic_store(p, v, __ATOMIC_RELAXED, __HIP_MEMORY_SCOPE_AGENT);
}
__device__ __forceinline__ unsigned long long ld_x64(const unsigned long long* p){
  return __hip_atomic_load(p, __ATOMIC_RELAXED, __HIP_MEMORY_SCOPE_AGENT);
}

// ---------------- prep kernels ----------------
__global__ void prep_convert(const float* __restrict__ Wih, const float* __restrict__ Whh,
                             const float* __restrict__ fcw, const float* __restrict__ bih,
                             const float* __restrict__ bhh,
                             _Float16* __restrict__ wh0, _Float16* __restrict__ wi1,
                             _Float16* __restrict__ wh1, _Float16* __restrict__ fcwh,
                             float* __restrict__ bias1)
{
  int i = blockIdx.x*256 + threadIdx.x;
  wh0[i] = (_Float16)Whh[i];
  wi1[i] = (_Float16)Wih[262144 + i];
  wh1[i] = (_Float16)Whh[262144 + i];
  if (i < 65536) fcwh[i] = (_Float16)fcw[i];
  if (i < 1024)  bias1[i] = bih[1024+i] + bhh[1024+i];
}

__global__ void prep_gx0(const float* __restrict__ x, const float* __restrict__ Wih,
                         const float* __restrict__ bih, const float* __restrict__ bhh,
                         float* __restrict__ gx0)
{
  int gid = blockIdx.x*256 + threadIdx.x;
  int b = gid >> 10, n = gid & 1023;
  const float4* xv = (const float4*)(x + (size_t)b*256);
  const float4* wv = (const float4*)(Wih + (size_t)n*256);
  float s = bih[n] + bhh[n];
  #pragma unroll 8
  for (int k=0;k<64;k++){
    float4 a = xv[k], c = wv[k];
    s += a.x*c.x + a.y*c.y + a.z*c.z + a.w*c.w;
  }
  gx0[gid] = s;
}

__global__ void zero_flags(unsigned* __restrict__ f){
  f[blockIdx.x*256 + threadIdx.x] = 0u;   // 64 blocks x 256 = 16384 words
}

// ================= Phase A: layer-0 recurrence =================
// 64 WGs = 16 batch-groups (16 rows) x 4 j-slices (64 cols).
// Weights slice (4 gates x 64 j) x 256 K = 128 KB in LDS. One exchange/step.
__global__ __launch_bounds__(512,1) void lstm_l0(
    const float* __restrict__ gx0, const _Float16* __restrict__ Wh0g,
    const float* __restrict__ h0_in, const float* __restrict__ c0_in,
    unsigned* __restrict__ seq0dw, unsigned* __restrict__ h0x,
    unsigned* __restrict__ flagA)
{
  __shared__ _Float16 W0s[256][256];   // 128 KB (16B-granule XOR swizzle per row)
  __shared__ _Float16 sh0[16][256];    // 8 KB
  __shared__ float    gbuf[4][16][66]; // 16.9 KB, stride 66 => ~2-way max

  const int blk = blockIdx.x;
  const int grp = blk >> 2;            // 0..15 batch group
  const int s   = blk & 3;             // j-slice
  const int b0  = grp*16;
  const int tid = threadIdx.x;
  const int wv  = tid >> 6, l = tid & 63;
  const int c16 = l & 15, kg = l >> 4;
  const int gate = wv >> 1, jblk = (wv & 1)*32;

  // weights -> LDS
  for (int idx = tid; idx < 8192; idx += 512){
    int row = idx >> 5, gr = idx & 31;
    int g = row >> 6, jl = row & 63;
    half8 v = *(const half8*)(Wh0g + ((size_t)(g*256 + s*64 + jl))*256 + gr*8);
    *(half8*)&W0s[row][(gr ^ (row&7))*8] = v;
  }
  // h0 init -> LDS
  {
    int row = tid >> 5, gr = tid & 31;
    const float* src = h0_in + (size_t)(b0+row)*256 + gr*8;
    half8 v;
    #pragma unroll
    for (int q=0;q<8;q++) v[q] = (_Float16)src[q];
    *(half8*)&sh0[row][(gr ^ (row&7))*8] = v;
  }
  // cell state: thread owns (eb, j=2jp, 2jp+1) within slice
  const int eb = tid >> 5, jp = tid & 31;
  float cA = c0_in[(size_t)(b0+eb)*256 + s*64 + 2*jp];
  float cB = c0_in[(size_t)(b0+eb)*256 + s*64 + 2*jp + 1];
  float gxr[2][4];
  #pragma unroll
  for (int nt=0;nt<2;nt++)
    #pragma unroll
    for (int r=0;r<4;r++)
      gxr[nt][r] = gx0[(size_t)(b0 + kg*4 + r)*1024 + gate*256 + s*64 + jblk + nt*16 + c16];

  unsigned* flg = flagA + grp*TSTEPS;
  const int r0 = gate*64 + jblk + c16;   // W0s row for acc0
  const int r1 = r0 + 16;                // for acc1
  __syncthreads();

  for (int t = 0; t < TSTEPS; ++t){
    f32x4 acc0 = { gxr[0][0], gxr[0][1], gxr[0][2], gxr[0][3] };
    f32x4 acc1 = { gxr[1][0], gxr[1][1], gxr[1][2], gxr[1][3] };
    #pragma unroll
    for (int kt=0;kt<8;kt++){
      half8 af  = *(const half8*)&sh0[c16][((kt*4+kg) ^ (c16&7))*8];
      half8 b0f = *(const half8*)&W0s[r0][((kt*4+kg) ^ (r0&7))*8];
      half8 b1f = *(const half8*)&W0s[r1][((kt*4+kg) ^ (r1&7))*8];
      acc0 = __builtin_amdgcn_mfma_f32_16x16x32_f16(af, b0f, acc0, 0,0,0);
      acc1 = __builtin_amdgcn_mfma_f32_16x16x32_f16(af, b1f, acc1, 0,0,0);
    }
    #pragma unroll
    for (int r=0;r<4;r++){
      gbuf[gate][kg*4+r][jblk + c16]      = acc0[r];
      gbuf[gate][kg*4+r][jblk + 16 + c16] = acc1[r];
    }
    __syncthreads();
    { // cell, 2 elems
      int j0 = 2*jp, j1 = 2*jp+1;
      float i0 = sigf (gbuf[0][eb][j0]), i1 = sigf (gbuf[0][eb][j1]);
      float f0 = sigf (gbuf[1][eb][j0]), f1 = sigf (gbuf[1][eb][j1]);
      float g0 = tanh_(gbuf[2][eb][j0]), g1 = tanh_(gbuf[2][eb][j1]);
      float o0 = sigf (gbuf[3][eb][j0]), o1 = sigf (gbuf[3][eb][j1]);
      cA = f0*cA + i0*g0;
      cB = f1*cB + i1*g1;
      float hA = o0*tanh_(cA), hB = o1*tanh_(cB);
      G16 pk; pk.h = half8{0,0,0,0,0,0,0,0};
      _Float16 a16 = (_Float16)hA, b16 = (_Float16)hB;
      unsigned u = (unsigned)__builtin_bit_cast(unsigned short, a16)
                 | ((unsigned)__builtin_bit_cast(unsigned short, b16) << 16);
      st_x(&h0x[(t&1)*32768 + (size_t)(b0+eb)*128 + s*32 + jp], u);
      seq0dw[((size_t)(b0+eb)*TSTEPS + t)*128 + s*32 + jp] = u;  // plain store
    }
    asm volatile("s_waitcnt vmcnt(0)" ::: "memory");
    __syncthreads();                       // all waves' stores at L3
    if (t+1 < TSTEPS){
      if (tid == 0){
        __hip_atomic_fetch_add(&flg[t], 1u, __ATOMIC_RELAXED, __HIP_MEMORY_SCOPE_AGENT);
        while (__hip_atomic_load(&flg[t], __ATOMIC_RELAXED, __HIP_MEMORY_SCOPE_AGENT) < 4u)
          __builtin_amdgcn_s_sleep(2);
      }
      __syncthreads();
      { // gather full 16x256 tile -> sh0
        int row = tid >> 5, gr = tid & 31;
        const unsigned long long* src =
          (const unsigned long long*)&h0x[(t&1)*32768 + (size_t)(b0+row)*128 + gr*4];
        G16 g16;
        g16.u2[0] = ld_x64(src);
        g16.u2[1] = ld_x64(src+1);
        *(half8*)&sh0[row][(gr ^ (row&7))*8] = g16.h;
      }
      __syncthreads();
    }
  }
}

// ================= Phase C: layer-1 recurrence =================
// 128 WGs = 16 batch-groups (16 rows) x 8 j-slices (32 cols).
// [Wi1|Wh1] slice = 128 rows x 512 K = 128 KB LDS. One exchange/step.
__global__ __launch_bounds__(512,1) void lstm_l1(
    const _Float16* __restrict__ Wi1g, const _Float16* __restrict__ Wh1g,
    const float* __restrict__ bias1, const float* __restrict__ h_in,
    const float* __restrict__ c0_in, const _Float16* __restrict__ seq0,
    unsigned* __restrict__ seq1dw, unsigned* __restrict__ h1x,
    unsigned* __restrict__ flagC)
{
  __shared__ _Float16 W1s[128][512];   // 128 KB
  __shared__ _Float16 sh0[16][256];    // 8 KB  h0(t)
  __shared__ _Float16 sh1[16][256];    // 8 KB  h1(t-1)
  __shared__ float    gbuf[4][16][34]; // 8.7 KB

  const int blk = blockIdx.x;
  const int grp = blk >> 3;            // 0..15
  const int js  = blk & 7;             // j-slice
  const int b0  = grp*16;
  const int jb  = js*32;
  const int tid = threadIdx.x;
  const int wv  = tid >> 6, l = tid & 63;
  const int c16 = l & 15, kg = l >> 4;
  const int gate = wv >> 1, jhalf = (wv & 1)*16;

  // weights -> LDS: row = gate*32 + jl ; k<256 Wi1, k>=256 Wh1
  for (int idx = tid; idx < 8192; idx += 512){
    int row = idx >> 6, gr = idx & 63;
    int g = row >> 5, jl = row & 31;
    size_t nrow = (size_t)(g*256 + jb + jl);
    const _Float16* src = (gr < 32) ? (Wi1g + nrow*256 + gr*8)
                                    : (Wh1g + nrow*256 + (size_t)(gr-32)*8);
    *(half8*)&W1s[row][(gr ^ (row&7))*8] = *(const half8*)src;
  }
  // sh1 init (h1(t=-1)) from h_in layer 1
  {
    int row = tid >> 5, gr = tid & 31;
    const float* src = h_in + 65536 + (size_t)(b0+row)*256 + gr*8;
    half8 v;
    #pragma unroll
    for (int q=0;q<8;q++) v[q] = (_Float16)src[q];
    *(half8*)&sh1[row][(gr ^ (row&7))*8] = v;
  }
  // sh0 init: h0(t=0) from seq0
  {
    int row = tid >> 5, gr = tid & 31;
    half8 v = *(const half8*)&seq0[((size_t)(b0+row)*TSTEPS + 0)*256 + gr*8];
    *(half8*)&sh0[row][(gr ^ (row&7))*8] = v;
  }
  // cell state: tid<256 own (eb, 2 j's)
  const int eb = tid >> 4, jp = tid & 15;   // valid when tid<256
  float cA = 0.f, cB = 0.f;
  if (tid < 256){
    cA = c0_in[65536 + (size_t)(b0+eb)*256 + jb + 2*jp];
    cB = c0_in[65536 + (size_t)(b0+eb)*256 + jb + 2*jp + 1];
  }
  const float bv = bias1[gate*256 + jb + jhalf + c16];
  const int nl = gate*32 + jhalf + c16;     // W1s row
  unsigned* flg = flagC + grp*TSTEPS;
  __syncthreads();

  for (int t = 0; t < TSTEPS; ++t){
    f32x4 acc = { bv, bv, bv, bv };
    #pragma unroll
    for (int kt=0;kt<8;kt++){               // Wi1 · h0(t)
      half8 af = *(const half8*)&sh0[c16][((kt*4+kg) ^ (c16&7))*8];
      half8 bf = *(const half8*)&W1s[nl][((kt*4+kg) ^ (nl&7))*8];
      acc = __builtin_amdgcn_mfma_f32_16x16x32_f16(af, bf, acc, 0,0,0);
    }
    #pragma unroll
    for (int kt=0;kt<8;kt++){               // Wh1 · h1(t-1)
      half8 af = *(const half8*)&sh1[c16][((kt*4+kg) ^ (c16&7))*8];
      half8 bf = *(const half8*)&W1s[nl][((32 + kt*4+kg) ^ (nl&7))*8];
      acc = __builtin_amdgcn_mfma_f32_16x16x32_f16(af, bf, acc, 0,0,0);
    }
    #pragma unroll
    for (int r=0;r<4;r++) gbuf[gate][kg*4+r][jhalf + c16] = acc[r];
    __syncthreads();
    if (tid < 256){ // cell, 2 elems
      int j0 = 2*jp, j1 = 2*jp+1;
      float i0 = sigf (gbuf[0][eb][j0]), i1 = sigf (gbuf[0][eb][j1]);
      float f0 = sigf (gbuf[1][eb][j0]), f1 = sigf (gbuf[1][eb][j1]);
      float g0 = tanh_(gbuf[2][eb][j0]), g1 = tanh_(gbuf[2][eb][j1]);
      float o0 = sigf (gbuf[3][eb][j0]), o1 = sigf (gbuf[3][eb][j1]);
      cA = f0*cA + i0*g0;
      cB = f1*cB + i1*g1;
      float hA = o0*tanh_(cA), hB = o1*tanh_(cB);
      _Float16 a16 = (_Float16)hA, b16 = (_Float16)hB;
      unsigned u = (unsigned)__builtin_bit_cast(unsigned short, a16)
                 | ((unsigned)__builtin_bit_cast(unsigned short, b16) << 16);
      st_x(&h1x[(t&1)*32768 + (size_t)(b0+eb)*128 + js*16 + jp], u);
      seq1dw[((size_t)(b0+eb)*TSTEPS + t)*256 + js*16 + jp] = u;   // pitch 512 f16
    }
    // stage h0(t+1) while the h1 exchange settles (sh0 reads all done)
    if (t+1 < TSTEPS){
      int row = tid >> 5, gr = tid & 31;
      half8 v = *(const half8*)&seq0[((size_t)(b0+row)*TSTEPS + (t+1))*256 + gr*8];
      *(half8*)&sh0[row][(gr ^ (row&7))*8] = v;
    }
    asm volatile("s_waitcnt vmcnt(0)" ::: "memory");
    __syncthreads();
    if (t+1 < TSTEPS){
      if (tid == 0){
        __hip_atomic_fetch_add(&flg[t], 1u, __ATOMIC_RELAXED, __HIP_MEMORY_SCOPE_AGENT);
        while (__hip_atomic_load(&flg[t], __ATOMIC_RELAXED, __HIP_MEMORY_SCOPE_AGENT) < 8u)
          __builtin_amdgcn_s_sleep(2);
      }
      __syncthreads();
      { // gather h1(t) -> sh1
        int row = tid >> 5, gr = tid & 31;
        const unsigned long long* src =
          (const unsigned long long*)&h1x[(t&1)*32768 + (size_t)(b0+row)*128 + gr*4];
        G16 g16;
        g16.u2[0] = ld_x64(src);
        g16.u2[1] = ld_x64(src+1);
        *(half8*)&sh1[row][(gr ^ (row&7))*8] = g16.h;
      }
      __syncthreads();
    }
  }
}

// ---------------- FC + log_softmax / softmax ----------------
__global__ __launch_bounds__(256) void fc_kernel(
    const _Float16* __restrict__ seq, int pitch,
    const _Float16* __restrict__ fcwh, const float* __restrict__ fcb,
    float* __restrict__ out0, float* __restrict__ out1)
{
  const int tid = threadIdx.x;
  const int w = tid >> 6, l = tid & 63;
  const int col = l & 15, kg = l >> 4;
  const size_t m0 = (size_t)blockIdx.x*64 + (size_t)w*16;
  half8 a[8];
  #pragma unroll
  for (int kt=0;kt<8;kt++)
    a[kt] = *(const half8*)&seq[(m0+col)*(size_t)pitch + kt*32 + kg*8];
  f32x4 acc[16];
  #pragma unroll
  for (int nt=0;nt<16;nt++){
    int n = nt*16 + col;
    float bvl = fcb[n];
    f32x4 c = {bvl,bvl,bvl,bvl};
    const _Float16* wr = fcwh + (size_t)n*256;
    #pragma unroll
    for (int kt=0;kt<8;kt++){
      half8 bf = *(const half8*)&wr[kt*32 + kg*8];
      c = __builtin_amdgcn_mfma_f32_16x16x32_f16(a[kt], bf, c, 0,0,0);
    }
    acc[nt] = c;
  }
  #pragma unroll
  for (int r=0;r<4;r++){
    float mx = -3.0e38f;
    #pragma unroll
    for (int nt=0;nt<16;nt++) mx = fmaxf(mx, acc[nt][r]);
    #pragma unroll
    for (int off=1; off<16; off<<=1) mx = fmaxf(mx, __shfl_xor(mx, off, 64));
    float s = 0.0f;
    #pragma unroll
    for (int nt=0;nt<16;nt++) s += __expf(acc[nt][r]-mx);
    #pragma unroll
    for (int off=1; off<16; off<<=1) s += __shfl_xor(s, off, 64);
    float inv = 1.0f/s;
    float ls  = __logf(s);
    size_t row = m0 + (size_t)kg*4 + r;
    #pragma unroll
    for (int nt=0;nt<16;nt++){
      int n = nt*16 + col;
      float v = acc[nt][r]-mx;
      out0[row*256 + n] = v - ls;
      out1[row*256 + n] = __expf(v)*inv;
    }
  }
}

extern "C" void kernel_launch(void* const* d_in, const int* in_sizes, int n_in,
                              void* d_out, int out_size, void* d_ws, size_t ws_size,
                              hipStream_t stream)
{
  const float* x   = (const float*)d_in[0];
  const float* h0  = (const float*)d_in[1];
  const float* c0  = (const float*)d_in[2];
  const float* Wih = (const float*)d_in[3];
  const float* Whh = (const float*)d_in[4];
  const float* bih = (const float*)d_in[5];
  const float* bhh = (const float*)d_in[6];
  const float* fcw = (const float*)d_in[7];
  const float* fcb = (const float*)d_in[8];
  (void)in_sizes; (void)n_in; (void)out_size; (void)ws_size;

  char* ws = (char*)d_ws;
  _Float16* wh0   = (_Float16*)(ws + 0);            // 512 KB
  _Float16* wi1   = (_Float16*)(ws + (512<<10));    // 512 KB
  _Float16* wh1   = (_Float16*)(ws + (1024<<10));   // 512 KB
  _Float16* fcwh  = (_Float16*)(ws + (1536<<10));   // 128 KB
  float*    bias1 = (float*)   (ws + (1664<<10));   // 4 KB
  float*    gx0   = (float*)   (ws + (1668<<10));   // 1 MB (ends ~2.7 MB)

  // d_out layout (out0 region scratch, all overwritten/unused before fc writes):
  //   [0,64MB)   seq0 (f16 b-major trajectory of layer-0 h)
  //   64MB       h0x exchange (2 x 128 KB)
  //   65MB       h1x exchange (2 x 128 KB)
  //   66MB       flagA (32 KB) ; flagC right after (32 KB)
  char* ob = (char*)d_out;
  float* out0 = (float*)d_out;
  float* out1 = out0 + (size_t)BATCH*TSTEPS*OUTC;
  unsigned* seq0dw = (unsigned*)ob;
  _Float16* seq0   = (_Float16*)ob;
  unsigned* h0x    = (unsigned*)(ob + (64ull<<20));
  unsigned* h1x    = (unsigned*)(ob + (65ull<<20));
  unsigned* flagA  = (unsigned*)(ob + (66ull<<20));
  unsigned* flagC  = flagA + 16*TSTEPS;
  unsigned* seq1dw = (unsigned*)out1;               // pitch 512 f16 overlay
  _Float16* seq1   = (_Float16*)out1;

  hipLaunchKernelGGL(zero_flags, dim3(64), dim3(256), 0, stream, flagA);
  hipLaunchKernelGGL(prep_convert, dim3(1024), dim3(256), 0, stream,
                     Wih, Whh, fcw, bih, bhh, wh0, wi1, wh1, fcwh, bias1);
  hipLaunchKernelGGL(prep_gx0, dim3(1024), dim3(256), 0, stream,
                     x, Wih, bih, bhh, gx0);
  hipLaunchKernelGGL(lstm_l0, dim3(64), dim3(512), 0, stream,
                     gx0, wh0, h0, c0, seq0dw, h0x, flagA);
  hipLaunchKernelGGL(lstm_l1, dim3(128), dim3(512), 0, stream,
                     wi1, wh1, bias1, h0, c0, seq0, seq1dw, h1x, flagC);
  hipLaunchKernelGGL(fc_kernel, dim3(2048), dim3(256), 0, stream,
                     seq1, 512, fcwh, fcb, out0, out1);
}

// Round 4
// 1834.691 us; speedup vs baseline: 15.9177x; 1.7731x over previous
//
#include <hip/hip_runtime.h>

#define TSTEPS 512
#define BATCH  256
#define HID    256
#define OUTC   256

typedef _Float16 half8 __attribute__((ext_vector_type(8)));
typedef float    f32x4 __attribute__((ext_vector_type(4)));

union G16 { unsigned long long u2[2]; unsigned u[4]; half8 h; };

// ring geometry: entry = u64 (lo: 2xf16 data, hi: tag = step+2; 0 = invalid)
// layout: [slot][grp(16)][row(16)][pair(128)]
#define H0_SLOTS 16
#define H1_SLOTS 4
#define H0RING_QW (H0_SLOTS*16*16*128)   // 524288 (4 MB)
#define H1RING_QW (H1_SLOTS*16*16*128)   // 131072 (1 MB)
#define FLAG_DW   (16*TSTEPS)            // l1 consumption acks

__device__ __forceinline__ float sigf(float x){ return 1.0f/(1.0f+__expf(-x)); }
__device__ __forceinline__ float tanh_(float x){
  float a = fminf(fmaxf(x,-8.0f),8.0f);
  float e = __expf(2.0f*a);
  return (e-1.0f)/(e+1.0f);
}
__device__ __forceinline__ void st64(unsigned long long* p, unsigned long long v){
  __hip_atomic_store(p, v, __ATOMIC_RELAXED, __HIP_MEMORY_SCOPE_AGENT);
}
__device__ __forceinline__ unsigned long long ld64(const unsigned long long* p){
  return __hip_atomic_load(p, __ATOMIC_RELAXED, __HIP_MEMORY_SCOPE_AGENT);
}
__device__ __forceinline__ unsigned pack2(float a, float b){
  _Float16 x=(_Float16)a, y=(_Float16)b;
  return (unsigned)__builtin_bit_cast(unsigned short,x)
       | ((unsigned)__builtin_bit_cast(unsigned short,y)<<16);
}

// ---------------- prep kernels ----------------
__global__ void prep_convert(const float* __restrict__ Wih, const float* __restrict__ Whh,
                             const float* __restrict__ fcw, const float* __restrict__ bih,
                             const float* __restrict__ bhh,
                             _Float16* __restrict__ wh0, _Float16* __restrict__ wi1,
                             _Float16* __restrict__ wh1, _Float16* __restrict__ fcwh,
                             float* __restrict__ bias1)
{
  int i = blockIdx.x*256 + threadIdx.x;
  wh0[i] = (_Float16)Whh[i];
  wi1[i] = (_Float16)Wih[262144 + i];
  wh1[i] = (_Float16)Whh[262144 + i];
  if (i < 65536) fcwh[i] = (_Float16)fcw[i];
  if (i < 1024)  bias1[i] = bih[1024+i] + bhh[1024+i];
}

__global__ void prep_gx0(const float* __restrict__ x, const float* __restrict__ Wih,
                         const float* __restrict__ bih, const float* __restrict__ bhh,
                         float* __restrict__ gx0)
{
  int gid = blockIdx.x*256 + threadIdx.x;
  int b = gid >> 10, n = gid & 1023;
  const float4* xv = (const float4*)(x + (size_t)b*256);
  const float4* wv = (const float4*)(Wih + (size_t)n*256);
  float s = bih[n] + bhh[n];
  #pragma unroll 8
  for (int k=0;k<64;k++){
    float4 a = xv[k], c = wv[k];
    s += a.x*c.x + a.y*c.y + a.z*c.z + a.w*c.w;
  }
  gx0[gid] = s;
}

// zero rings + flags (replay safety: stale tags from prior replay alias)
__global__ void zero_scratch(unsigned long long* __restrict__ base){
  size_t i = (size_t)blockIdx.x*256 + threadIdx.x;   // grid sized exactly
  st64(base + i, 0ull);
}

// seed h(-1): h0ring slot 15, h1ring slot 3, tag 1
__global__ void seed_rings(const float* __restrict__ h_in,
                           unsigned long long* __restrict__ h0ring,
                           unsigned long long* __restrict__ h1ring)
{
  int idx = blockIdx.x*256 + threadIdx.x;   // 32768
  int b = idx >> 7, pair = idx & 127;
  int grp = b >> 4, row = b & 15;
  const float* s0 = h_in + (size_t)b*256 + 2*pair;
  const float* s1 = s0 + 65536;
  unsigned long long v0 = (1ull<<32) | pack2(s0[0], s0[1]);
  unsigned long long v1 = (1ull<<32) | pack2(s1[0], s1[1]);
  st64(&h0ring[(((size_t)15*16+grp)*16+row)*128 + pair], v0);
  st64(&h1ring[(((size_t) 3*16+grp)*16+row)*128 + pair], v1);
}

// poll one 16x256 f16 tile from a ring into swizzled LDS (512 threads)
__device__ __forceinline__ void poll_tile(const unsigned long long* __restrict__ ring,
                                          int slot, int grp, unsigned tag,
                                          _Float16* __restrict__ shdst, int tid)
{
  int row = tid >> 5, q = tid & 31;
  const unsigned long long* p = ring + (((size_t)slot*16+grp)*16 + row)*128 + q*4;
  unsigned long long v0,v1,v2,v3;
  for (;;){
    v0 = ld64(p);   v1 = ld64(p+1);
    v2 = ld64(p+2); v3 = ld64(p+3);
    if ((unsigned)(v0>>32)==tag && (unsigned)(v1>>32)==tag &&
        (unsigned)(v2>>32)==tag && (unsigned)(v3>>32)==tag) break;
    __builtin_amdgcn_s_sleep(1);
  }
  G16 g;
  g.u[0]=(unsigned)v0; g.u[1]=(unsigned)v1; g.u[2]=(unsigned)v2; g.u[3]=(unsigned)v3;
  *(half8*)&shdst[row*256 + (q ^ (row&7))*8] = g.h;
}

// ================= fused pipelined 2-layer LSTM =================
// 192 WGs: blk<64 -> layer0 (16 grps x 4 j-slices of 64 cols)
//          blk>=64 -> layer1 (16 grps x 8 j-slices of 32 cols)
// h0: l0 produces into h0ring (D=16); consumed by l0 peers (recurrence) and
//     l1 (feed-forward). l1 acks per (grp,t); l0 throttles at t-16.
// h1: l1 internal, D=4 (tag protocol bounds skew; no ack needed).
__global__ __launch_bounds__(512,1) void lstm_fused(
    const float* __restrict__ gx0, const _Float16* __restrict__ Wh0g,
    const _Float16* __restrict__ Wi1g, const _Float16* __restrict__ Wh1g,
    const float* __restrict__ bias1, const float* __restrict__ c0_in,
    unsigned* __restrict__ seq1dw,
    unsigned long long* __restrict__ h0ring,
    unsigned long long* __restrict__ h1ring,
    unsigned* __restrict__ flagC)
{
  __shared__ __align__(16) _Float16 Ws[65536];   // 128 KB weights
  __shared__ __align__(16) _Float16 shA[4096];   // 8 KB  (h0 tile)
  __shared__ __align__(16) char     Rg[16896];   // l0: gbuf[4][16][66]f
                                                 // l1: sh1[16][256]h + gbuf[4][16][34]f
  const int blk = blockIdx.x;
  const int tid = threadIdx.x;
  const int wv  = tid >> 6, l = tid & 63;
  const int c16 = l & 15, kg = l >> 4;

  if (blk < 64){
    // ---------------- layer 0 role ----------------
    const int grp = blk >> 2, s = blk & 3;
    const int b0  = grp*16;
    const int gate = wv >> 1, jblk = (wv & 1)*32;
    float (*gbuf)[16][66] = (float (*)[16][66])Rg;

    for (int idx = tid; idx < 8192; idx += 512){
      int row = idx >> 5, gr = idx & 31;
      int g = row >> 6, jl = row & 63;
      half8 v = *(const half8*)(Wh0g + ((size_t)(g*256 + s*64 + jl))*256 + gr*8);
      *(half8*)&Ws[row*256 + (gr ^ (row&7))*8] = v;
    }
    const int eb = tid >> 5, jp = tid & 31;
    float cA = c0_in[(size_t)(b0+eb)*256 + s*64 + 2*jp];
    float cB = c0_in[(size_t)(b0+eb)*256 + s*64 + 2*jp + 1];
    float gxr[2][4];
    #pragma unroll
    for (int nt=0;nt<2;nt++)
      #pragma unroll
      for (int r=0;r<4;r++)
        gxr[nt][r] = gx0[(size_t)(b0 + kg*4 + r)*1024 + gate*256 + s*64 + jblk + nt*16 + c16];
    const int r0 = gate*64 + jblk + c16;
    const int r1 = r0 + 16;
    __syncthreads();

    for (int t = 0; t < TSTEPS; ++t){
      // consume h0(t-1): slot (t-1)&15, tag t+1
      poll_tile(h0ring, (t-1)&(H0_SLOTS-1), grp, (unsigned)(t+1), shA, tid);
      if (tid == 0 && t >= H0_SLOTS){
        const unsigned* f = flagC + grp*TSTEPS + (t - H0_SLOTS);
        while (__hip_atomic_load(f, __ATOMIC_RELAXED, __HIP_MEMORY_SCOPE_AGENT) < 8u)
          __builtin_amdgcn_s_sleep(2);
      }
      __syncthreads();

      f32x4 acc0 = { gxr[0][0], gxr[0][1], gxr[0][2], gxr[0][3] };
      f32x4 acc1 = { gxr[1][0], gxr[1][1], gxr[1][2], gxr[1][3] };
      #pragma unroll
      for (int kt=0;kt<8;kt++){
        half8 af  = *(const half8*)&shA[c16*256 + ((kt*4+kg) ^ (c16&7))*8];
        half8 b0f = *(const half8*)&Ws[r0*256 + ((kt*4+kg) ^ (r0&7))*8];
        half8 b1f = *(const half8*)&Ws[r1*256 + ((kt*4+kg) ^ (r1&7))*8];
        acc0 = __builtin_amdgcn_mfma_f32_16x16x32_f16(af, b0f, acc0, 0,0,0);
        acc1 = __builtin_amdgcn_mfma_f32_16x16x32_f16(af, b1f, acc1, 0,0,0);
      }
      #pragma unroll
      for (int r=0;r<4;r++){
        gbuf[gate][kg*4+r][jblk + c16]      = acc0[r];
        gbuf[gate][kg*4+r][jblk + 16 + c16] = acc1[r];
      }
      __syncthreads();
      { // cell: 1 pair per thread; publish h0(t) with tag t+2
        int j0 = 2*jp, j1 = 2*jp+1;
        float i0 = sigf (gbuf[0][eb][j0]), i1 = sigf (gbuf[0][eb][j1]);
        float f0 = sigf (gbuf[1][eb][j0]), f1 = sigf (gbuf[1][eb][j1]);
        float g0 = tanh_(gbuf[2][eb][j0]), g1 = tanh_(gbuf[2][eb][j1]);
        float o0 = sigf (gbuf[3][eb][j0]), o1 = sigf (gbuf[3][eb][j1]);
        cA = f0*cA + i0*g0;
        cB = f1*cB + i1*g1;
        unsigned d = pack2(o0*tanh_(cA), o1*tanh_(cB));
        st64(&h0ring[(((size_t)(t&(H0_SLOTS-1))*16+grp)*16+eb)*128 + s*32+jp],
             ((unsigned long long)(unsigned)(t+2)<<32) | d);
      }
      // no extra barrier: next poll's shA overwrite is gated by the barriers above
    }
  } else {
    // ---------------- layer 1 role ----------------
    const int bb  = blk - 64;
    const int grp = bb >> 3, js = bb & 7;
    const int b0  = grp*16, jb = js*32;
    const int gate = wv >> 1, jhalf = (wv & 1)*16;
    _Float16* sh1 = (_Float16*)Rg;                       // [16][256]
    float (*gbuf)[16][34] = (float (*)[16][34])(Rg + 8192);

    for (int idx = tid; idx < 8192; idx += 512){
      int row = idx >> 6, gr = idx & 63;
      int g = row >> 5, jl = row & 31;
      size_t nrow = (size_t)(g*256 + jb + jl);
      const _Float16* src = (gr < 32) ? (Wi1g + nrow*256 + gr*8)
                                      : (Wh1g + nrow*256 + (size_t)(gr-32)*8);
      *(half8*)&Ws[row*512 + (gr ^ (row&7))*8] = *(const half8*)src;
    }
    const int eb = tid >> 4, jp = tid & 15;   // producers: tid<256
    float cA = 0.f, cB = 0.f;
    if (tid < 256){
      cA = c0_in[65536 + (size_t)(b0+eb)*256 + jb + 2*jp];
      cB = c0_in[65536 + (size_t)(b0+eb)*256 + jb + 2*jp + 1];
    }
    const float bv = bias1[gate*256 + jb + jhalf + c16];
    const int nl = gate*32 + jhalf + c16;
    __syncthreads();

    for (int t = 0; t < TSTEPS; ++t){
      // consume h0(t): slot t&15, tag t+2 (l0 runs ahead; usually no wait)
      poll_tile(h0ring, t&(H0_SLOTS-1), grp, (unsigned)(t+2), shA, tid);
      __syncthreads();
      if (tid == 0)
        __hip_atomic_fetch_add(flagC + grp*TSTEPS + t, 1u,
                               __ATOMIC_RELAXED, __HIP_MEMORY_SCOPE_AGENT);
      // part A: bias + Wi1 . h0(t)   (hides part of the h1 exchange latency)
      f32x4 acc = { bv, bv, bv, bv };
      #pragma unroll
      for (int kt=0;kt<8;kt++){
        half8 af = *(const half8*)&shA[c16*256 + ((kt*4+kg) ^ (c16&7))*8];
        half8 bf = *(const half8*)&Ws[nl*512 + ((kt*4+kg) ^ (nl&7))*8];
        acc = __builtin_amdgcn_mfma_f32_16x16x32_f16(af, bf, acc, 0,0,0);
      }
      // consume h1(t-1): slot (t-1)&3, tag t+1
      poll_tile(h1ring, (t-1)&(H1_SLOTS-1), grp, (unsigned)(t+1), sh1, tid);
      __syncthreads();
      // part B: += Wh1 . h1(t-1)
      #pragma unroll
      for (int kt=0;kt<8;kt++){
        half8 af = *(const half8*)&sh1[c16*256 + ((kt*4+kg) ^ (c16&7))*8];
        half8 bf = *(const half8*)&Ws[nl*512 + ((32 + kt*4+kg) ^ (nl&7))*8];
        acc = __builtin_amdgcn_mfma_f32_16x16x32_f16(af, bf, acc, 0,0,0);
      }
      #pragma unroll
      for (int r=0;r<4;r++) gbuf[gate][kg*4+r][jhalf + c16] = acc[r];
      __syncthreads();
      if (tid < 256){ // cell + publish h1(t) tag t+2 + seq1
        int j0 = 2*jp, j1 = 2*jp+1;
        float i0 = sigf (gbuf[0][eb][j0]), i1 = sigf (gbuf[0][eb][j1]);
        float f0 = sigf (gbuf[1][eb][j0]), f1 = sigf (gbuf[1][eb][j1]);
        float g0 = tanh_(gbuf[2][eb][j0]), g1 = tanh_(gbuf[2][eb][j1]);
        float o0 = sigf (gbuf[3][eb][j0]), o1 = sigf (gbuf[3][eb][j1]);
        cA = f0*cA + i0*g0;
        cB = f1*cB + i1*g1;
        unsigned d = pack2(o0*tanh_(cA), o1*tanh_(cB));
        st64(&h1ring[(((size_t)(t&(H1_SLOTS-1))*16+grp)*16+eb)*128 + js*16+jp],
             ((unsigned long long)(unsigned)(t+2)<<32) | d);
        seq1dw[((size_t)(b0+eb)*TSTEPS + t)*256 + js*16 + jp] = d;  // pitch 512 f16
      }
    }
  }
}

// ---------------- FC + log_softmax / softmax ----------------
__global__ __launch_bounds__(256) void fc_kernel(
    const _Float16* __restrict__ seq, int pitch,
    const _Float16* __restrict__ fcwh, const float* __restrict__ fcb,
    float* __restrict__ out0, float* __restrict__ out1)
{
  const int tid = threadIdx.x;
  const int w = tid >> 6, l = tid & 63;
  const int col = l & 15, kg = l >> 4;
  const size_t m0 = (size_t)blockIdx.x*64 + (size_t)w*16;
  half8 a[8];
  #pragma unroll
  for (int kt=0;kt<8;kt++)
    a[kt] = *(const half8*)&seq[(m0+col)*(size_t)pitch + kt*32 + kg*8];
  f32x4 acc[16];
  #pragma unroll
  for (int nt=0;nt<16;nt++){
    int n = nt*16 + col;
    float bvl = fcb[n];
    f32x4 c = {bvl,bvl,bvl,bvl};
    const _Float16* wr = fcwh + (size_t)n*256;
    #pragma unroll
    for (int kt=0;kt<8;kt++){
      half8 bf = *(const half8*)&wr[kt*32 + kg*8];
      c = __builtin_amdgcn_mfma_f32_16x16x32_f16(a[kt], bf, c, 0,0,0);
    }
    acc[nt] = c;
  }
  #pragma unroll
  for (int r=0;r<4;r++){
    float mx = -3.0e38f;
    #pragma unroll
    for (int nt=0;nt<16;nt++) mx = fmaxf(mx, acc[nt][r]);
    #pragma unroll
    for (int off=1; off<16; off<<=1) mx = fmaxf(mx, __shfl_xor(mx, off, 64));
    float s = 0.0f;
    #pragma unroll
    for (int nt=0;nt<16;nt++) s += __expf(acc[nt][r]-mx);
    #pragma unroll
    for (int off=1; off<16; off<<=1) s += __shfl_xor(s, off, 64);
    float inv = 1.0f/s;
    float ls  = __logf(s);
    size_t row = m0 + (size_t)kg*4 + r;
    #pragma unroll
    for (int nt=0;nt<16;nt++){
      int n = nt*16 + col;
      float v = acc[nt][r]-mx;
      out0[row*256 + n] = v - ls;
      out1[row*256 + n] = __expf(v)*inv;
    }
  }
}

extern "C" void kernel_launch(void* const* d_in, const int* in_sizes, int n_in,
                              void* d_out, int out_size, void* d_ws, size_t ws_size,
                              hipStream_t stream)
{
  const float* x   = (const float*)d_in[0];
  const float* h0  = (const float*)d_in[1];
  const float* c0  = (const float*)d_in[2];
  const float* Wih = (const float*)d_in[3];
  const float* Whh = (const float*)d_in[4];
  const float* bih = (const float*)d_in[5];
  const float* bhh = (const float*)d_in[6];
  const float* fcw = (const float*)d_in[7];
  const float* fcb = (const float*)d_in[8];
  (void)in_sizes; (void)n_in; (void)out_size; (void)ws_size;

  char* ws = (char*)d_ws;
  _Float16* wh0   = (_Float16*)(ws + 0);            // 512 KB
  _Float16* wi1   = (_Float16*)(ws + (512<<10));    // 512 KB
  _Float16* wh1   = (_Float16*)(ws + (1024<<10));   // 512 KB
  _Float16* fcwh  = (_Float16*)(ws + (1536<<10));   // 128 KB
  float*    bias1 = (float*)   (ws + (1664<<10));   // 4 KB
  float*    gx0   = (float*)   (ws + (1668<<10));   // 1 MB (ends ~2.7 MB)

  // scratch in out0 (fc overwrites all of it at the end):
  //   h0ring 4 MB | h1ring 1 MB | flagC 32 KB
  float* out0 = (float*)d_out;
  float* out1 = out0 + (size_t)BATCH*TSTEPS*OUTC;
  unsigned long long* h0ring = (unsigned long long*)d_out;
  unsigned long long* h1ring = h0ring + H0RING_QW;
  unsigned*           flagC  = (unsigned*)(h1ring + H1RING_QW);
  unsigned* seq1dw = (unsigned*)out1;               // seq1 overlay, pitch 512 f16
  _Float16* seq1   = (_Float16*)out1;

  const int zeroQW = H0RING_QW + H1RING_QW + FLAG_DW/2;   // 659456 u64
  hipLaunchKernelGGL(zero_scratch, dim3(zeroQW/256), dim3(256), 0, stream, h0ring);
  hipLaunchKernelGGL(prep_convert, dim3(1024), dim3(256), 0, stream,
                     Wih, Whh, fcw, bih, bhh, wh0, wi1, wh1, fcwh, bias1);
  hipLaunchKernelGGL(prep_gx0, dim3(1024), dim3(256), 0, stream,
                     x, Wih, bih, bhh, gx0);
  hipLaunchKernelGGL(seed_rings, dim3(128), dim3(256), 0, stream, h0, h0ring, h1ring);
  hipLaunchKernelGGL(lstm_fused, dim3(192), dim3(512), 0, stream,
                     gx0, wh0, wi1, wh1, bias1, c0, seq1dw, h0ring, h1ring, flagC);
  hipLaunchKernelGGL(fc_kernel, dim3(2048), dim3(256), 0, stream,
                     seq1, 512, fcwh, fcb, out0, out1);
}